// Round 9
// baseline (4396.281 us; speedup 1.0000x reference)
//
#include <hip/hip_runtime.h>
#include <math.h>

// Problem constants
#define TT 512
#define BB 64
#define EE 300
#define HD 256
#define KK 20
#define NG 1024        // gate rows per direction
#define RGC 8          // row-groups (8 rows each)
#define RPBF 8         // rows per block
#define HS 260         // LDS h row stride (floats), padded
#define LDSF (RPBF * HS)          // one direction's h buffer (2080 floats)
#define LDS_FLOATS (2 * 2 * LDSF) // double-buffered x 2 dirs = 8320 floats = 33 KB
#define HXS 2048                  // u64 per (parity,dir,rg) slice: 256 dims x 8 rows

// Relaxed agent-scope atomics = cache-bypassing LLC ops (no fences anywhere;
// W/P stay cache-resident). Proven correct across prior rounds (absmax 0).
__device__ __forceinline__ unsigned long long ldg_llc_u64(const unsigned long long* p) {
    return __hip_atomic_load(p, __ATOMIC_RELAXED, __HIP_MEMORY_SCOPE_AGENT);
}
__device__ __forceinline__ void stg_llc_u64(unsigned long long* p, unsigned long long v) {
    __hip_atomic_store(p, v, __ATOMIC_RELAXED, __HIP_MEMORY_SCOPE_AGENT);
}
// pack h + step-tag into one self-validating word (tag = step+1; memset-0 == "h(-1) valid")
__device__ __forceinline__ unsigned long long pack_ht(float h, int tag) {
    return ((unsigned long long)(unsigned)tag << 32) | (unsigned long long)__float_as_uint(h);
}

// ============================================================
// K1: fused embedding-gather + input projection GEMM (fp32)
// P layout: [slot][row(64)][gate(1024)] (gate innermost).  (unchanged, proven)
// ============================================================
__global__ __launch_bounds__(256) void proj_kernel(
    const int* __restrict__ sentence, const float* __restrict__ embed,
    const float* __restrict__ Wf_ih, const float* __restrict__ bf,
    const float* __restrict__ Wb_ih, const float* __restrict__ bb,
    float* __restrict__ Pf, float* __restrict__ Pb, int t0f, int t0b)
{
    __shared__ float As[32][BB];
    __shared__ float Ws[32][64];
    const int s   = blockIdx.x;
    const int gb  = blockIdx.y;
    const int dir = gb >> 4;
    const int g0  = (gb & 15) * 64;
    const int tg  = dir ? (t0b + s) : (t0f + s);
    const int tid = threadIdx.x;
    const int tx = tid & 15, ty = tid >> 4;

    const int lrow = tid >> 2;
    const int kq   = tid & 3;
    const int word = sentence[lrow * TT + tg];
    const float* arow = embed + (size_t)word * EE;
    const float* Wih  = dir ? Wb_ih : Wf_ih;
    const float* bias = dir ? bb : bf;
    const float* wrow = Wih + (size_t)(g0 + lrow) * EE;

    float acc[4][4] = {};
    for (int k0 = 0; k0 < EE; k0 += 32) {
        __syncthreads();
        #pragma unroll
        for (int u = 0; u < 8; ++u) {
            const int k  = kq * 8 + u;
            const int kk = k0 + k;
            const bool ok = (kk < EE);
            As[k][lrow] = ok ? arow[kk] : 0.f;
            Ws[k][lrow] = ok ? wrow[kk] : 0.f;
        }
        __syncthreads();
        #pragma unroll
        for (int k = 0; k < 32; ++k) {
            const float4 a = *(const float4*)&As[k][ty * 4];
            const float4 w = *(const float4*)&Ws[k][tx * 4];
            acc[0][0] += a.x*w.x; acc[0][1] += a.x*w.y; acc[0][2] += a.x*w.z; acc[0][3] += a.x*w.w;
            acc[1][0] += a.y*w.x; acc[1][1] += a.y*w.y; acc[1][2] += a.y*w.z; acc[1][3] += a.y*w.w;
            acc[2][0] += a.z*w.x; acc[2][1] += a.z*w.y; acc[2][2] += a.z*w.z; acc[2][3] += a.z*w.w;
            acc[3][0] += a.w*w.x; acc[3][1] += a.w*w.y; acc[3][2] += a.w*w.z; acc[3][3] += a.w*w.w;
        }
    }
    float* Pd = (dir ? Pb : Pf) + (size_t)s * BB * NG;
    const float4 bv = *(const float4*)&bias[g0 + tx * 4];
    #pragma unroll
    for (int i = 0; i < 4; ++i) {
        float4 v;
        v.x = acc[i][0] + bv.x; v.y = acc[i][1] + bv.y;
        v.z = acc[i][2] + bv.z; v.w = acc[i][3] + bv.w;
        *(float4*)(Pd + (size_t)(ty * 4 + i) * NG + g0 + tx * 4) = v;
    }
}

// GEMV core (R5..R8-proven math): W in regs, h from LDS, partials over this
// lane's 16-k slice for 8 rows x 4 gates, then recursive-halving butterfly
// over the 16 s-lanes (static indices; values halve per round).
// End: lane s (and s+8, duplicated) holds row (s&7)'s 4 full gate sums.
__device__ __forceinline__ void gemv8(const float* __restrict__ base,
                                      const float4 (&wr)[4][4], int s,
                                      float res[4])
{
    float acc[4][8];
    #pragma unroll
    for (int g = 0; g < 4; ++g)
        #pragma unroll
        for (int r = 0; r < 8; ++r) acc[g][r] = 0.f;

    #pragma unroll
    for (int r = 0; r < 8; ++r) {
        const float* hr = base + r * HS + 4 * s;
        const float4 h0 = *(const float4*)(hr + 0);
        const float4 h1 = *(const float4*)(hr + 64);
        const float4 h2 = *(const float4*)(hr + 128);
        const float4 h3 = *(const float4*)(hr + 192);
        #pragma unroll
        for (int g = 0; g < 4; ++g) {
            float a4 = acc[g][r];
            a4 = fmaf(wr[g][0].x, h0.x, a4); a4 = fmaf(wr[g][0].y, h0.y, a4);
            a4 = fmaf(wr[g][0].z, h0.z, a4); a4 = fmaf(wr[g][0].w, h0.w, a4);
            a4 = fmaf(wr[g][1].x, h1.x, a4); a4 = fmaf(wr[g][1].y, h1.y, a4);
            a4 = fmaf(wr[g][1].z, h1.z, a4); a4 = fmaf(wr[g][1].w, h1.w, a4);
            a4 = fmaf(wr[g][2].x, h2.x, a4); a4 = fmaf(wr[g][2].y, h2.y, a4);
            a4 = fmaf(wr[g][2].z, h2.z, a4); a4 = fmaf(wr[g][2].w, h2.w, a4);
            a4 = fmaf(wr[g][3].x, h3.x, a4); a4 = fmaf(wr[g][3].y, h3.y, a4);
            a4 = fmaf(wr[g][3].z, h3.z, a4); a4 = fmaf(wr[g][3].w, h3.w, a4);
            acc[g][r] = a4;
        }
    }
    float r1[4][4];
    #pragma unroll
    for (int g = 0; g < 4; ++g)
        #pragma unroll
        for (int m = 0; m < 4; ++m) {
            const float sendv = (s & 1) ? acc[g][2*m]   : acc[g][2*m+1];
            const float keepv = (s & 1) ? acc[g][2*m+1] : acc[g][2*m];
            r1[g][m] = keepv + __shfl_xor(sendv, 1);
        }
    float r2[4][2];
    #pragma unroll
    for (int g = 0; g < 4; ++g)
        #pragma unroll
        for (int m = 0; m < 2; ++m) {
            const float sendv = (s & 2) ? r1[g][2*m]   : r1[g][2*m+1];
            const float keepv = (s & 2) ? r1[g][2*m+1] : r1[g][2*m];
            r2[g][m] = keepv + __shfl_xor(sendv, 2);
        }
    #pragma unroll
    for (int g = 0; g < 4; ++g) {
        const float sendv = (s & 4) ? r2[g][0] : r2[g][1];
        const float keepv = (s & 4) ? r2[g][1] : r2[g][0];
        const float r3 = keepv + __shfl_xor(sendv, 4);
        res[g] = r3 + __shfl_xor(r3, 8);
    }
}

// ============================================================
// K2: WAVE-SPECIALIZED dual-direction LSTM; W PINNED in VGPRs via opaque
// asm (R8's VGPR=80 proved the compiler was reloading W from L2 inside the
// GEMV — the dominant per-step cost). Single barrier per step with
// double-buffered LDS h-stage (barrier bounds inter-wave skew to <1 iter, so
// stage(u+1) can only coexist with gemv(u) which reads the other buffer).
// 256 blocks x 256 threads (1 block/CU). blk&7 = row-group rg (8 rows);
// jg = blk>>3 = dim-group (8 dims). Waves 0-1 = fwd, waves 2-3 = bwd.
// Tag protocol / parity slots / memset-0 init / transitive overwrite-safety:
// verbatim R8 (program order per wave: verify(t) precedes publish(t+2)).
// ============================================================
__global__ __launch_bounds__(256, 1) void lstm_kernel(
    const float* __restrict__ Pf, const float* __restrict__ Pb,
    const float* __restrict__ Wf_hh, const float* __restrict__ Wb_hh,
    const int* __restrict__ lengths,
    float* __restrict__ HF, float* __restrict__ HB,
    unsigned long long* __restrict__ hx2,  // [parity][dir][rg8][dim 256][row 8] u64
    float* __restrict__ cbuf,              // [dir][dim 256][row 64]
    int step0, int nsteps)
{
    __shared__ float lds[LDS_FLOATS];    // [buf(u&1)][dir][2080]
    const int blk  = blockIdx.x;
    const int rg   = blk & 7;            // row-group (XCD residue)
    const int jg   = blk >> 3;           // dim-group 0..31
    const int tid  = threadIdx.x;
    const int w    = tid >> 6;           // wave 0..3
    const int dirw = w >> 1;             // 0 = fwd (waves 0,1), 1 = bwd (waves 2,3)
    const int wh   = w & 1;              // dim half within this direction
    const int lane = tid & 63;
    const int d    = lane >> 4;          // dim-within-wave 0..3
    const int s    = lane & 15;          // k-slice 0..15
    const int rs   = s & 7;              // owned row 0..7 (dup at s, s+8)
    const int dg   = jg * 8 + wh * 4 + d;     // global dim 0..255
    const int grow = rg * RPBF + rs;          // global batch row
    const int kb   = tid >> 3;           // stage role: dim base 0..31
    const int rr   = tid & 7;            // stage role: row 0..7

    const float* Whh = dirw ? Wb_hh : Wf_hh;
    const float* P   = dirw ? Pb : Pf;
    float* Hout      = dirw ? HB : HF;
    const int len    = lengths[grow];

    // ---- own direction's W_hh slice -> registers (64 VGPR)
    float4 wR[4][4];
    #pragma unroll
    for (int g = 0; g < 4; ++g) {
        const float* wrow = Whh + (size_t)(g * HD + dg) * HD + 4 * s;
        #pragma unroll
        for (int q = 0; q < 4; ++q)
            wR[g][q] = *(const float4*)(wrow + 64 * q);
    }
    // PIN: opaque asm makes each component an asm-defined value — the
    // compiler cannot rematerialize it from memory (R8's failure mode).
    #pragma unroll
    for (int g = 0; g < 4; ++g)
        #pragma unroll
        for (int q = 0; q < 4; ++q)
            asm volatile("" : "+v"(wR[g][q].x), "+v"(wR[g][q].y),
                              "+v"(wR[g][q].z), "+v"(wR[g][q].w));

    // ---- cell state (own direction only)
    float c0 = cbuf[((size_t)dirw * HD + dg) * BB + grow];

    // ---- prologue: load + verify BOTH dirs h(step0-1) (tag step0, parity (step0+1)&1)
    unsigned long long hF[8], hB[8];
    {
        const unsigned long long* s0F = hx2 + ((size_t)(((step0 + 1) & 1) * 2 + 0) * RGC + rg) * HXS;
        const unsigned long long* s0B = hx2 + ((size_t)(((step0 + 1) & 1) * 2 + 1) * RGC + rg) * HXS;
        #pragma unroll
        for (int it = 0; it < 8; ++it) {
            hF[it] = ldg_llc_u64(&s0F[(kb + 32 * it) * 8 + rr]);
            hB[it] = ldg_llc_u64(&s0B[(kb + 32 * it) * 8 + rr]);
        }
        #pragma unroll
        for (int it = 0; it < 8; ++it) {
            unsigned long long v = hF[it];
            if ((int)(v >> 32) != step0) {
                const unsigned long long* a = &s0F[(kb + 32 * it) * 8 + rr];
                do { v = ldg_llc_u64(a); } while ((int)(v >> 32) != step0);
            }
            hF[it] = v;
            v = hB[it];
            if ((int)(v >> 32) != step0) {
                const unsigned long long* a = &s0B[(kb + 32 * it) * 8 + rr];
                do { v = ldg_llc_u64(a); } while ((int)(v >> 32) != step0);
            }
            hB[it] = v;
        }
    }

    for (int u = 0; u < nsteps; ++u) {
        const int gs   = step0 + u;
        const int pbt  = TT - 1 - gs;    // original time index for bwd
        const int p    = dirw ? pbt : gs;
        const int slot = dirw ? (nsteps - 1 - u) : u;

        // P terms (own dir, h-independent), issued early
        const float* Pp = P + ((size_t)slot * BB + grow) * NG + dg;
        const float pi = Pp[0], pf = Pp[256], pg = Pp[512], po = Pp[768];

        // stage verified h(gs-1), both dirs -> LDS buf[u&1]
        float* bufF = lds + (u & 1) * (2 * LDSF);
        float* bufB = bufF + LDSF;
        #pragma unroll
        for (int it = 0; it < 8; ++it) {
            bufF[rr * HS + kb + 32 * it] =
                __uint_as_float((unsigned)(hF[it] & 0xffffffffull));
            bufB[rr * HS + kb + 32 * it] =
                __uint_as_float((unsigned)(hB[it] & 0xffffffffull));
        }
        __syncthreads();   // the ONLY barrier: all staged; bounds skew < 1 iter

        // GEMV (own direction, W pinned in registers)
        float res[4];
        gemv8(dirw ? bufB : bufF, wR, s, res);

        // cell math (one row, one dim, own dir)
        const float ig = 1.f / (1.f + expf(-(res[0] + pi)));
        const float fg = 1.f / (1.f + expf(-(res[1] + pf)));
        const float og = 1.f / (1.f + expf(-(res[3] + po)));
        const float gt = tanhf(res[2] + pg);
        float cn = fg * c0 + ig * gt;
        float hn = og * tanhf(cn);
        if (dirw) {                      // bwd rows inactive until p < len
            const bool v0 = (pbt < len);
            c0 = v0 ? cn : c0;  hn = v0 ? hn : 0.f;
        } else {
            c0 = cn;
        }

        // publish (h, tag gs+1), fire-and-forget; lazy H write
        if (s < 8) {
            stg_llc_u64(&hx2[((size_t)((gs & 1) * 2 + dirw) * RGC + rg) * HXS
                             + (size_t)dg * 8 + rs], pack_ht(hn, gs + 1));
            Hout[((size_t)p * HD + dg) * BB + grow] = hn;
        }

        // issue + verify next step's h(gs) (tag gs+1, parity gs&1), both dirs.
        // Common path: one OR-reduced check; slow path: per-word spin.
        if (u + 1 < nsteps) {
            const unsigned long long* sF = hx2 + ((size_t)((gs & 1) * 2 + 0) * RGC + rg) * HXS;
            const unsigned long long* sB = hx2 + ((size_t)((gs & 1) * 2 + 1) * RGC + rg) * HXS;
            #pragma unroll
            for (int it = 0; it < 8; ++it) {
                hF[it] = ldg_llc_u64(&sF[(kb + 32 * it) * 8 + rr]);
                hB[it] = ldg_llc_u64(&sB[(kb + 32 * it) * 8 + rr]);
            }
            unsigned bad = 0;
            #pragma unroll
            for (int it = 0; it < 8; ++it) {
                bad |= (unsigned)(hF[it] >> 32) ^ (unsigned)(gs + 1);
                bad |= (unsigned)(hB[it] >> 32) ^ (unsigned)(gs + 1);
            }
            if (bad) {
                #pragma unroll
                for (int it = 0; it < 8; ++it) {
                    unsigned long long v = hF[it];
                    if ((int)(v >> 32) != gs + 1) {
                        const unsigned long long* a = &sF[(kb + 32 * it) * 8 + rr];
                        do { v = ldg_llc_u64(a); } while ((int)(v >> 32) != gs + 1);
                    }
                    hF[it] = v;
                    v = hB[it];
                    if ((int)(v >> 32) != gs + 1) {
                        const unsigned long long* a = &sB[(kb + 32 * it) * 8 + rr];
                        do { v = ldg_llc_u64(a); } while ((int)(v >> 32) != gs + 1);
                    }
                    hB[it] = v;
                }
            }
        }
        // no second barrier: stage(u+1) writes buf[(u+1)&1], disjoint from
        // buf[u&1] that any slower wave may still be reading in gemv(u).
    }

    if (s < 8)
        cbuf[((size_t)dirw * HD + dg) * BB + grow] = c0;
}

// ============================================================
// K3: emissions = [hf|hb] @ W_out^T + b_out -> emis[t][b][20]
// H layout [t][d][b].  (unchanged, proven)
// ============================================================
__global__ __launch_bounds__(256) void emis_kernel(
    const float* __restrict__ HF, const float* __restrict__ HB,
    const float* __restrict__ W_out, const float* __restrict__ b_out,
    float* __restrict__ emis)
{
    const int t = blockIdx.x;
    const int b = threadIdx.x & 63;
    int jg = threadIdx.x >> 6;
    jg = __builtin_amdgcn_readfirstlane(jg);

    float acc[5];
    #pragma unroll
    for (int u = 0; u < 5; ++u) acc[u] = b_out[jg + 4 * u];

    const float* hf = HF + (size_t)t * HD * BB + b;
    const float* hb = HB + (size_t)t * HD * BB + b;
    for (int k = 0; k < HD; ++k) {
        const float hv = hf[(size_t)k * BB];
        #pragma unroll
        for (int u = 0; u < 5; ++u)
            acc[u] = fmaf(hv, W_out[(size_t)(jg + 4 * u) * 512 + k], acc[u]);
    }
    for (int k = 0; k < HD; ++k) {
        const float hv = hb[(size_t)k * BB];
        #pragma unroll
        for (int u = 0; u < 5; ++u)
            acc[u] = fmaf(hv, W_out[(size_t)(jg + 4 * u) * 512 + HD + k], acc[u]);
    }
    #pragma unroll
    for (int u = 0; u < 5; ++u)
        emis[((size_t)t * BB + b) * KK + jg + 4 * u] = acc[u];
}

// ============================================================
// K4: Viterbi per batch row; exact first-max argmax; bp in LDS. (unchanged)
// ============================================================
__global__ __launch_bounds__(64) void viterbi_kernel(
    const float* __restrict__ emis, const int* __restrict__ lengths,
    const float* __restrict__ trans, const int* __restrict__ stop_id_p,
    float* __restrict__ out)
{
    __shared__ float tr[KK * KK];
    __shared__ float delta[KK], nd[KK];
    __shared__ unsigned char bp[TT][KK];
    const int b = blockIdx.x;
    const int tid = threadIdx.x;
    for (int i = tid; i < KK * KK; i += 64) tr[i] = trans[i];
    if (tid < KK) delta[tid] = 0.f;
    const int len = lengths[b];
    __syncthreads();

    for (int t = 0; t < TT; ++t) {
        if (tid < KK) {
            if (t < len) {
                float best = delta[0] + tr[tid * KK + 0];
                int am = 0;
                for (int p2 = 1; p2 < KK; ++p2) {
                    const float v = delta[p2] + tr[tid * KK + p2];
                    if (v > best) { best = v; am = p2; }
                }
                nd[tid] = best + emis[((size_t)t * BB + b) * KK + tid];
                bp[t][tid] = (unsigned char)am;
            } else {
                nd[tid] = delta[tid];
                bp[t][tid] = (unsigned char)tid;
            }
        }
        __syncthreads();
        if (tid < KK) delta[tid] = nd[tid];
        __syncthreads();
    }

    if (tid == 0) {
        const int stop_id = *stop_id_p;
        float best = delta[0] + tr[stop_id * KK + 0];
        int bl = 0;
        for (int jx = 1; jx < KK; ++jx) {
            const float v = delta[jx] + tr[stop_id * KK + jx];
            if (v > best) { best = v; bl = jx; }
        }
        out[b] = best;
        float* pout = out + BB + (size_t)b * (TT + 1);
        pout[TT] = (float)bl;
        int tag = bl;
        for (int t = TT - 1; t >= 0; --t) {
            tag = bp[t][tag];
            pout[t] = (float)tag;
        }
    }
}

// ============================================================
extern "C" void kernel_launch(void* const* d_in, const int* in_sizes, int n_in,
                              void* d_out, int out_size, void* d_ws, size_t ws_size,
                              hipStream_t stream) {
    const int*   sentence = (const int*)d_in[0];
    const int*   lengths  = (const int*)d_in[1];
    const int*   stop_id  = (const int*)d_in[3];
    const float* embed    = (const float*)d_in[4];
    const float* Wf_ih    = (const float*)d_in[5];
    const float* Wf_hh    = (const float*)d_in[6];
    const float* bf       = (const float*)d_in[7];
    const float* Wb_ih    = (const float*)d_in[8];
    const float* Wb_hh    = (const float*)d_in[9];
    const float* bb       = (const float*)d_in[10];
    const float* W_out    = (const float*)d_in[11];
    const float* b_out    = (const float*)d_in[12];
    const float* trans    = (const float*)d_in[13];
    float* out = (float*)d_out;

    const size_t hf_elems   = (size_t)TT * HD * BB;
    const size_t emis_elems = (size_t)TT * BB * KK;
    const size_t hx_u64     = (size_t)2 * 2 * RGC * HD * RPBF; // 65536 u64
    const size_t cbuf_elems = (size_t)2 * HD * BB;             // 32768
    const size_t fixed_bytes = (2 * hf_elems + emis_elems + cbuf_elems) * 4 + hx_u64 * 8;

    int CH = 0;
    const int cands[6] = {256, 128, 64, 32, 16, 8};
    for (int i = 0; i < 6; ++i) {
        const size_t need = fixed_bytes + 2ull * cands[i] * BB * NG * 4;
        if (need <= ws_size) { CH = cands[i]; break; }
    }
    if (CH == 0) return;

    float* Pf    = (float*)d_ws;
    float* Pb    = Pf + (size_t)CH * BB * NG;
    float* HF    = Pb + (size_t)CH * BB * NG;
    float* HB    = HF + hf_elems;
    float* emis  = HB + hf_elems;
    unsigned long long* hx2 = (unsigned long long*)(emis + emis_elems); // 8B-aligned (even float offset)
    float* cbuf  = (float*)(hx2 + hx_u64);

    // zero hx2 (tags 0 == valid initial h(-1)) + cbuf — contiguous region
    hipMemsetAsync(hx2, 0, hx_u64 * 8 + cbuf_elems * 4, stream);

    const int nch = TT / CH;
    for (int c = 0; c < nch; ++c) {
        const int t0f = c * CH;
        const int t0b = TT - (c + 1) * CH;
        proj_kernel<<<dim3(CH, 32), 256, 0, stream>>>(
            sentence, embed, Wf_ih, bf, Wb_ih, bb, Pf, Pb, t0f, t0b);
        lstm_kernel<<<dim3(256), 256, 0, stream>>>(
            Pf, Pb, Wf_hh, Wb_hh, lengths, HF, HB, hx2, cbuf, c * CH, CH);
    }
    emis_kernel<<<dim3(TT), 256, 0, stream>>>(HF, HB, W_out, b_out, emis);
    viterbi_kernel<<<dim3(BB), 64, 0, stream>>>(emis, lengths, trans, stop_id, out);
}

// Round 10
// 3877.613 us; speedup vs baseline: 1.1338x; 1.1338x over previous
//
#include <hip/hip_runtime.h>
#include <math.h>

// Problem constants
#define TT 512
#define BB 64
#define EE 300
#define HD 256
#define KK 20
#define NG 1024        // gate rows per direction
#define RGC 8          // row-groups (8 rows each)
#define RPBF 8         // rows per block
#define HS 260         // LDS h row stride (floats), padded
#define LDSF (RPBF * HS)          // one direction's h buffer (2080 floats)
#define LDS_FLOATS (2 * 2 * LDSF) // double-buffered x 2 dirs = 8320 floats = 33 KB
#define HXS 2048                  // u64 per (parity,dir,rg) slice: 256 dims x 8 rows

// Relaxed agent-scope atomics = cache-bypassing LLC ops (no fences anywhere;
// W/P stay cache-resident). Proven correct across prior rounds (absmax 0).
__device__ __forceinline__ unsigned long long ldg_llc_u64(const unsigned long long* p) {
    return __hip_atomic_load(p, __ATOMIC_RELAXED, __HIP_MEMORY_SCOPE_AGENT);
}
__device__ __forceinline__ void stg_llc_u64(unsigned long long* p, unsigned long long v) {
    __hip_atomic_store(p, v, __ATOMIC_RELAXED, __HIP_MEMORY_SCOPE_AGENT);
}
// pack h + step-tag into one self-validating word (tag = step+1; memset-0 == "h(-1) valid")
__device__ __forceinline__ unsigned long long pack_ht(float h, int tag) {
    return ((unsigned long long)(unsigned)tag << 32) | (unsigned long long)__float_as_uint(h);
}

// ============================================================
// K1: fused embedding-gather + input projection GEMM (fp32)
// P layout: [slot][row(64)][gate(1024)] (gate innermost).  (unchanged, proven)
// ============================================================
__global__ __launch_bounds__(256) void proj_kernel(
    const int* __restrict__ sentence, const float* __restrict__ embed,
    const float* __restrict__ Wf_ih, const float* __restrict__ bf,
    const float* __restrict__ Wb_ih, const float* __restrict__ bb,
    float* __restrict__ Pf, float* __restrict__ Pb, int t0f, int t0b)
{
    __shared__ float As[32][BB];
    __shared__ float Ws[32][64];
    const int s   = blockIdx.x;
    const int gb  = blockIdx.y;
    const int dir = gb >> 4;
    const int g0  = (gb & 15) * 64;
    const int tg  = dir ? (t0b + s) : (t0f + s);
    const int tid = threadIdx.x;
    const int tx = tid & 15, ty = tid >> 4;

    const int lrow = tid >> 2;
    const int kq   = tid & 3;
    const int word = sentence[lrow * TT + tg];
    const float* arow = embed + (size_t)word * EE;
    const float* Wih  = dir ? Wb_ih : Wf_ih;
    const float* bias = dir ? bb : bf;
    const float* wrow = Wih + (size_t)(g0 + lrow) * EE;

    float acc[4][4] = {};
    for (int k0 = 0; k0 < EE; k0 += 32) {
        __syncthreads();
        #pragma unroll
        for (int u = 0; u < 8; ++u) {
            const int k  = kq * 8 + u;
            const int kk = k0 + k;
            const bool ok = (kk < EE);
            As[k][lrow] = ok ? arow[kk] : 0.f;
            Ws[k][lrow] = ok ? wrow[kk] : 0.f;
        }
        __syncthreads();
        #pragma unroll
        for (int k = 0; k < 32; ++k) {
            const float4 a = *(const float4*)&As[k][ty * 4];
            const float4 w = *(const float4*)&Ws[k][tx * 4];
            acc[0][0] += a.x*w.x; acc[0][1] += a.x*w.y; acc[0][2] += a.x*w.z; acc[0][3] += a.x*w.w;
            acc[1][0] += a.y*w.x; acc[1][1] += a.y*w.y; acc[1][2] += a.y*w.z; acc[1][3] += a.y*w.w;
            acc[2][0] += a.z*w.x; acc[2][1] += a.z*w.y; acc[2][2] += a.z*w.z; acc[2][3] += a.z*w.w;
            acc[3][0] += a.w*w.x; acc[3][1] += a.w*w.y; acc[3][2] += a.w*w.z; acc[3][3] += a.w*w.w;
        }
    }
    float* Pd = (dir ? Pb : Pf) + (size_t)s * BB * NG;
    const float4 bv = *(const float4*)&bias[g0 + tx * 4];
    #pragma unroll
    for (int i = 0; i < 4; ++i) {
        float4 v;
        v.x = acc[i][0] + bv.x; v.y = acc[i][1] + bv.y;
        v.z = acc[i][2] + bv.z; v.w = acc[i][3] + bv.w;
        *(float4*)(Pd + (size_t)(ty * 4 + i) * NG + g0 + tx * 4) = v;
    }
}

// GEMV core (R5..R9-proven math): W in regs, h from LDS, partials over this
// lane's 16-k slice for 8 rows x 4 gates, then recursive-halving butterfly
// over the 16 s-lanes (static indices; values halve per round).
// End: lane s (and s+8, duplicated) holds row (s&7)'s 4 full gate sums.
__device__ __forceinline__ void gemv8(const float* __restrict__ base,
                                      const float4 (&wr)[4][4], int s,
                                      float res[4])
{
    float acc[4][8];
    #pragma unroll
    for (int g = 0; g < 4; ++g)
        #pragma unroll
        for (int r = 0; r < 8; ++r) acc[g][r] = 0.f;

    #pragma unroll
    for (int r = 0; r < 8; ++r) {
        const float* hr = base + r * HS + 4 * s;
        const float4 h0 = *(const float4*)(hr + 0);
        const float4 h1 = *(const float4*)(hr + 64);
        const float4 h2 = *(const float4*)(hr + 128);
        const float4 h3 = *(const float4*)(hr + 192);
        #pragma unroll
        for (int g = 0; g < 4; ++g) {
            float a4 = acc[g][r];
            a4 = fmaf(wr[g][0].x, h0.x, a4); a4 = fmaf(wr[g][0].y, h0.y, a4);
            a4 = fmaf(wr[g][0].z, h0.z, a4); a4 = fmaf(wr[g][0].w, h0.w, a4);
            a4 = fmaf(wr[g][1].x, h1.x, a4); a4 = fmaf(wr[g][1].y, h1.y, a4);
            a4 = fmaf(wr[g][1].z, h1.z, a4); a4 = fmaf(wr[g][1].w, h1.w, a4);
            a4 = fmaf(wr[g][2].x, h2.x, a4); a4 = fmaf(wr[g][2].y, h2.y, a4);
            a4 = fmaf(wr[g][2].z, h2.z, a4); a4 = fmaf(wr[g][2].w, h2.w, a4);
            a4 = fmaf(wr[g][3].x, h3.x, a4); a4 = fmaf(wr[g][3].y, h3.y, a4);
            a4 = fmaf(wr[g][3].z, h3.z, a4); a4 = fmaf(wr[g][3].w, h3.w, a4);
            acc[g][r] = a4;
        }
    }
    float r1[4][4];
    #pragma unroll
    for (int g = 0; g < 4; ++g)
        #pragma unroll
        for (int m = 0; m < 4; ++m) {
            const float sendv = (s & 1) ? acc[g][2*m]   : acc[g][2*m+1];
            const float keepv = (s & 1) ? acc[g][2*m+1] : acc[g][2*m];
            r1[g][m] = keepv + __shfl_xor(sendv, 1);
        }
    float r2[4][2];
    #pragma unroll
    for (int g = 0; g < 4; ++g)
        #pragma unroll
        for (int m = 0; m < 2; ++m) {
            const float sendv = (s & 2) ? r1[g][2*m]   : r1[g][2*m+1];
            const float keepv = (s & 2) ? r1[g][2*m+1] : r1[g][2*m];
            r2[g][m] = keepv + __shfl_xor(sendv, 2);
        }
    #pragma unroll
    for (int g = 0; g < 4; ++g) {
        const float sendv = (s & 4) ? r2[g][0] : r2[g][1];
        const float keepv = (s & 4) ? r2[g][1] : r2[g][0];
        const float r3 = keepv + __shfl_xor(sendv, 4);
        res[g] = r3 + __shfl_xor(r3, 8);
    }
}

// ============================================================
// K2: WAVE-SPECIALIZED dual-direction LSTM; W pinned in VGPRs, and
// amdgpu_waves_per_eu(1,1) raises the allocator's register budget to 512
// so the pin lands in VGPRs instead of scratch (R9: VGPR=76 + scratch
// spills; R8: VGPR=80 + L2 remat — both the same occupancy heuristic).
// Single barrier per step with double-buffered LDS h-stage (barrier bounds
// inter-wave skew to <1 iter; stage(u+1) writes the buffer gemv(u) isn't
// reading). 256 blocks x 256 threads (1 block/CU). blk&7 = row-group rg;
// jg = blk>>3 = dim-group (8 dims). Waves 0-1 = fwd, waves 2-3 = bwd.
// Tag protocol / parity slots / memset-0 init / transitive overwrite-safety:
// verbatim R8/R9.
// ============================================================
__global__ __launch_bounds__(256)
__attribute__((amdgpu_waves_per_eu(1, 1)))
void lstm_kernel(
    const float* __restrict__ Pf, const float* __restrict__ Pb,
    const float* __restrict__ Wf_hh, const float* __restrict__ Wb_hh,
    const int* __restrict__ lengths,
    float* __restrict__ HF, float* __restrict__ HB,
    unsigned long long* __restrict__ hx2,  // [parity][dir][rg8][dim 256][row 8] u64
    float* __restrict__ cbuf,              // [dir][dim 256][row 64]
    int step0, int nsteps)
{
    __shared__ float lds[LDS_FLOATS];    // [buf(u&1)][dir][2080]
    const int blk  = blockIdx.x;
    const int rg   = blk & 7;            // row-group (XCD residue)
    const int jg   = blk >> 3;           // dim-group 0..31
    const int tid  = threadIdx.x;
    const int w    = tid >> 6;           // wave 0..3
    const int dirw = w >> 1;             // 0 = fwd (waves 0,1), 1 = bwd (waves 2,3)
    const int wh   = w & 1;              // dim half within this direction
    const int lane = tid & 63;
    const int d    = lane >> 4;          // dim-within-wave 0..3
    const int s    = lane & 15;          // k-slice 0..15
    const int rs   = s & 7;              // owned row 0..7 (dup at s, s+8)
    const int dg   = jg * 8 + wh * 4 + d;     // global dim 0..255
    const int grow = rg * RPBF + rs;          // global batch row
    const int kb   = tid >> 3;           // stage role: dim base 0..31
    const int rr   = tid & 7;            // stage role: row 0..7

    const float* Whh = dirw ? Wb_hh : Wf_hh;
    const float* P   = dirw ? Pb : Pf;
    float* Hout      = dirw ? HB : HF;
    const int len    = lengths[grow];

    // ---- own direction's W_hh slice -> registers (64 VGPR)
    float4 wR[4][4];
    #pragma unroll
    for (int g = 0; g < 4; ++g) {
        const float* wrow = Whh + (size_t)(g * HD + dg) * HD + 4 * s;
        #pragma unroll
        for (int q = 0; q < 4; ++q)
            wR[g][q] = *(const float4*)(wrow + 64 * q);
    }
    // PIN: opaque asm makes each component an asm-defined value — cannot be
    // rematerialized; with waves_per_eu(1,1) the allocator keeps it in VGPRs.
    #pragma unroll
    for (int g = 0; g < 4; ++g)
        #pragma unroll
        for (int q = 0; q < 4; ++q)
            asm volatile("" : "+v"(wR[g][q].x), "+v"(wR[g][q].y),
                              "+v"(wR[g][q].z), "+v"(wR[g][q].w));

    // ---- cell state (own direction only)
    float c0 = cbuf[((size_t)dirw * HD + dg) * BB + grow];

    // ---- prologue: load + verify BOTH dirs h(step0-1) (tag step0, parity (step0+1)&1)
    unsigned long long hF[8], hB[8];
    {
        const unsigned long long* s0F = hx2 + ((size_t)(((step0 + 1) & 1) * 2 + 0) * RGC + rg) * HXS;
        const unsigned long long* s0B = hx2 + ((size_t)(((step0 + 1) & 1) * 2 + 1) * RGC + rg) * HXS;
        #pragma unroll
        for (int it = 0; it < 8; ++it) {
            hF[it] = ldg_llc_u64(&s0F[(kb + 32 * it) * 8 + rr]);
            hB[it] = ldg_llc_u64(&s0B[(kb + 32 * it) * 8 + rr]);
        }
        #pragma unroll
        for (int it = 0; it < 8; ++it) {
            unsigned long long v = hF[it];
            if ((int)(v >> 32) != step0) {
                const unsigned long long* a = &s0F[(kb + 32 * it) * 8 + rr];
                do { v = ldg_llc_u64(a); } while ((int)(v >> 32) != step0);
            }
            hF[it] = v;
            v = hB[it];
            if ((int)(v >> 32) != step0) {
                const unsigned long long* a = &s0B[(kb + 32 * it) * 8 + rr];
                do { v = ldg_llc_u64(a); } while ((int)(v >> 32) != step0);
            }
            hB[it] = v;
        }
    }

    for (int u = 0; u < nsteps; ++u) {
        const int gs   = step0 + u;
        const int pbt  = TT - 1 - gs;    // original time index for bwd
        const int p    = dirw ? pbt : gs;
        const int slot = dirw ? (nsteps - 1 - u) : u;

        // P terms (own dir, h-independent), issued early
        const float* Pp = P + ((size_t)slot * BB + grow) * NG + dg;
        const float pi = Pp[0], pf = Pp[256], pg = Pp[512], po = Pp[768];

        // stage verified h(gs-1), both dirs -> LDS buf[u&1]
        float* bufF = lds + (u & 1) * (2 * LDSF);
        float* bufB = bufF + LDSF;
        #pragma unroll
        for (int it = 0; it < 8; ++it) {
            bufF[rr * HS + kb + 32 * it] =
                __uint_as_float((unsigned)(hF[it] & 0xffffffffull));
            bufB[rr * HS + kb + 32 * it] =
                __uint_as_float((unsigned)(hB[it] & 0xffffffffull));
        }
        __syncthreads();   // the ONLY barrier: all staged; bounds skew < 1 iter

        // GEMV (own direction, W pinned in registers)
        float res[4];
        gemv8(dirw ? bufB : bufF, wR, s, res);

        // cell math (one row, one dim, own dir)
        const float ig = 1.f / (1.f + expf(-(res[0] + pi)));
        const float fg = 1.f / (1.f + expf(-(res[1] + pf)));
        const float og = 1.f / (1.f + expf(-(res[3] + po)));
        const float gt = tanhf(res[2] + pg);
        float cn = fg * c0 + ig * gt;
        float hn = og * tanhf(cn);
        if (dirw) {                      // bwd rows inactive until p < len
            const bool v0 = (pbt < len);
            c0 = v0 ? cn : c0;  hn = v0 ? hn : 0.f;
        } else {
            c0 = cn;
        }

        // publish (h, tag gs+1), fire-and-forget; lazy H write
        if (s < 8) {
            stg_llc_u64(&hx2[((size_t)((gs & 1) * 2 + dirw) * RGC + rg) * HXS
                             + (size_t)dg * 8 + rs], pack_ht(hn, gs + 1));
            Hout[((size_t)p * HD + dg) * BB + grow] = hn;
        }

        // issue + verify next step's h(gs) (tag gs+1, parity gs&1), both dirs.
        // Common path: one OR-reduced check; slow path: per-word spin.
        if (u + 1 < nsteps) {
            const unsigned long long* sF = hx2 + ((size_t)((gs & 1) * 2 + 0) * RGC + rg) * HXS;
            const unsigned long long* sB = hx2 + ((size_t)((gs & 1) * 2 + 1) * RGC + rg) * HXS;
            #pragma unroll
            for (int it = 0; it < 8; ++it) {
                hF[it] = ldg_llc_u64(&sF[(kb + 32 * it) * 8 + rr]);
                hB[it] = ldg_llc_u64(&sB[(kb + 32 * it) * 8 + rr]);
            }
            unsigned bad = 0;
            #pragma unroll
            for (int it = 0; it < 8; ++it) {
                bad |= (unsigned)(hF[it] >> 32) ^ (unsigned)(gs + 1);
                bad |= (unsigned)(hB[it] >> 32) ^ (unsigned)(gs + 1);
            }
            if (bad) {
                #pragma unroll
                for (int it = 0; it < 8; ++it) {
                    unsigned long long v = hF[it];
                    if ((int)(v >> 32) != gs + 1) {
                        const unsigned long long* a = &sF[(kb + 32 * it) * 8 + rr];
                        do { v = ldg_llc_u64(a); } while ((int)(v >> 32) != gs + 1);
                    }
                    hF[it] = v;
                    v = hB[it];
                    if ((int)(v >> 32) != gs + 1) {
                        const unsigned long long* a = &sB[(kb + 32 * it) * 8 + rr];
                        do { v = ldg_llc_u64(a); } while ((int)(v >> 32) != gs + 1);
                    }
                    hB[it] = v;
                }
            }
        }
        // no second barrier: stage(u+1) writes buf[(u+1)&1], disjoint from
        // buf[u&1] that any slower wave may still be reading in gemv(u).
    }

    if (s < 8)
        cbuf[((size_t)dirw * HD + dg) * BB + grow] = c0;
}

// ============================================================
// K3: emissions = [hf|hb] @ W_out^T + b_out -> emis[t][b][20]
// H layout [t][d][b].  (unchanged, proven)
// ============================================================
__global__ __launch_bounds__(256) void emis_kernel(
    const float* __restrict__ HF, const float* __restrict__ HB,
    const float* __restrict__ W_out, const float* __restrict__ b_out,
    float* __restrict__ emis)
{
    const int t = blockIdx.x;
    const int b = threadIdx.x & 63;
    int jg = threadIdx.x >> 6;
    jg = __builtin_amdgcn_readfirstlane(jg);

    float acc[5];
    #pragma unroll
    for (int u = 0; u < 5; ++u) acc[u] = b_out[jg + 4 * u];

    const float* hf = HF + (size_t)t * HD * BB + b;
    const float* hb = HB + (size_t)t * HD * BB + b;
    for (int k = 0; k < HD; ++k) {
        const float hv = hf[(size_t)k * BB];
        #pragma unroll
        for (int u = 0; u < 5; ++u)
            acc[u] = fmaf(hv, W_out[(size_t)(jg + 4 * u) * 512 + k], acc[u]);
    }
    for (int k = 0; k < HD; ++k) {
        const float hv = hb[(size_t)k * BB];
        #pragma unroll
        for (int u = 0; u < 5; ++u)
            acc[u] = fmaf(hv, W_out[(size_t)(jg + 4 * u) * 512 + HD + k], acc[u]);
    }
    #pragma unroll
    for (int u = 0; u < 5; ++u)
        emis[((size_t)t * BB + b) * KK + jg + 4 * u] = acc[u];
}

// ============================================================
// K4: Viterbi per batch row; exact first-max argmax; bp in LDS. (unchanged)
// ============================================================
__global__ __launch_bounds__(64) void viterbi_kernel(
    const float* __restrict__ emis, const int* __restrict__ lengths,
    const float* __restrict__ trans, const int* __restrict__ stop_id_p,
    float* __restrict__ out)
{
    __shared__ float tr[KK * KK];
    __shared__ float delta[KK], nd[KK];
    __shared__ unsigned char bp[TT][KK];
    const int b = blockIdx.x;
    const int tid = threadIdx.x;
    for (int i = tid; i < KK * KK; i += 64) tr[i] = trans[i];
    if (tid < KK) delta[tid] = 0.f;
    const int len = lengths[b];
    __syncthreads();

    for (int t = 0; t < TT; ++t) {
        if (tid < KK) {
            if (t < len) {
                float best = delta[0] + tr[tid * KK + 0];
                int am = 0;
                for (int p2 = 1; p2 < KK; ++p2) {
                    const float v = delta[p2] + tr[tid * KK + p2];
                    if (v > best) { best = v; am = p2; }
                }
                nd[tid] = best + emis[((size_t)t * BB + b) * KK + tid];
                bp[t][tid] = (unsigned char)am;
            } else {
                nd[tid] = delta[tid];
                bp[t][tid] = (unsigned char)tid;
            }
        }
        __syncthreads();
        if (tid < KK) delta[tid] = nd[tid];
        __syncthreads();
    }

    if (tid == 0) {
        const int stop_id = *stop_id_p;
        float best = delta[0] + tr[stop_id * KK + 0];
        int bl = 0;
        for (int jx = 1; jx < KK; ++jx) {
            const float v = delta[jx] + tr[stop_id * KK + jx];
            if (v > best) { best = v; bl = jx; }
        }
        out[b] = best;
        float* pout = out + BB + (size_t)b * (TT + 1);
        pout[TT] = (float)bl;
        int tag = bl;
        for (int t = TT - 1; t >= 0; --t) {
            tag = bp[t][tag];
            pout[t] = (float)tag;
        }
    }
}

// ============================================================
extern "C" void kernel_launch(void* const* d_in, const int* in_sizes, int n_in,
                              void* d_out, int out_size, void* d_ws, size_t ws_size,
                              hipStream_t stream) {
    const int*   sentence = (const int*)d_in[0];
    const int*   lengths  = (const int*)d_in[1];
    const int*   stop_id  = (const int*)d_in[3];
    const float* embed    = (const float*)d_in[4];
    const float* Wf_ih    = (const float*)d_in[5];
    const float* Wf_hh    = (const float*)d_in[6];
    const float* bf       = (const float*)d_in[7];
    const float* Wb_ih    = (const float*)d_in[8];
    const float* Wb_hh    = (const float*)d_in[9];
    const float* bb       = (const float*)d_in[10];
    const float* W_out    = (const float*)d_in[11];
    const float* b_out    = (const float*)d_in[12];
    const float* trans    = (const float*)d_in[13];
    float* out = (float*)d_out;

    const size_t hf_elems   = (size_t)TT * HD * BB;
    const size_t emis_elems = (size_t)TT * BB * KK;
    const size_t hx_u64     = (size_t)2 * 2 * RGC * HD * RPBF; // 65536 u64
    const size_t cbuf_elems = (size_t)2 * HD * BB;             // 32768
    const size_t fixed_bytes = (2 * hf_elems + emis_elems + cbuf_elems) * 4 + hx_u64 * 8;

    int CH = 0;
    const int cands[6] = {256, 128, 64, 32, 16, 8};
    for (int i = 0; i < 6; ++i) {
        const size_t need = fixed_bytes + 2ull * cands[i] * BB * NG * 4;
        if (need <= ws_size) { CH = cands[i]; break; }
    }
    if (CH == 0) return;

    float* Pf    = (float*)d_ws;
    float* Pb    = Pf + (size_t)CH * BB * NG;
    float* HF    = Pb + (size_t)CH * BB * NG;
    float* HB    = HF + hf_elems;
    float* emis  = HB + hf_elems;
    unsigned long long* hx2 = (unsigned long long*)(emis + emis_elems); // 8B-aligned (even float offset)
    float* cbuf  = (float*)(hx2 + hx_u64);

    // zero hx2 (tags 0 == valid initial h(-1)) + cbuf — contiguous region
    hipMemsetAsync(hx2, 0, hx_u64 * 8 + cbuf_elems * 4, stream);

    const int nch = TT / CH;
    for (int c = 0; c < nch; ++c) {
        const int t0f = c * CH;
        const int t0b = TT - (c + 1) * CH;
        proj_kernel<<<dim3(CH, 32), 256, 0, stream>>>(
            sentence, embed, Wf_ih, bf, Wb_ih, bb, Pf, Pb, t0f, t0b);
        lstm_kernel<<<dim3(256), 256, 0, stream>>>(
            Pf, Pb, Wf_hh, Wb_hh, lengths, HF, HB, hx2, cbuf, c * CH, CH);
    }
    emis_kernel<<<dim3(TT), 256, 0, stream>>>(HF, HB, W_out, b_out, emis);
    viterbi_kernel<<<dim3(BB), 64, 0, stream>>>(emis, lengths, trans, stop_id, out);
}

// Round 11
// 3762.600 us; speedup vs baseline: 1.1684x; 1.0306x over previous
//
#include <hip/hip_runtime.h>
#include <math.h>

// Problem constants
#define TT 512
#define BB 64
#define EE 300
#define HD 256
#define KK 20
#define NG 1024        // gate rows per direction
#define RGC 16         // row-groups (4 rows each)
#define RPBF 4         // rows per block
#define HS 260         // LDS h row stride (floats), padded
#define LDSF (RPBF * HS)          // one direction's h buffer (1040 floats)
#define LDS_FLOATS (2 * 2 * LDSF) // double-buffered x 2 dirs = 4160 floats = 16.6 KB
#define HXS 1024                  // u64 per (parity,dir,rg) slice: 256 dims x 4 rows

// Relaxed agent-scope atomics = cache-bypassing LLC ops (no fences anywhere;
// W/P stay cache-resident). Proven correct across prior rounds (absmax 0).
__device__ __forceinline__ unsigned long long ldg_llc_u64(const unsigned long long* p) {
    return __hip_atomic_load(p, __ATOMIC_RELAXED, __HIP_MEMORY_SCOPE_AGENT);
}
__device__ __forceinline__ void stg_llc_u64(unsigned long long* p, unsigned long long v) {
    __hip_atomic_store(p, v, __ATOMIC_RELAXED, __HIP_MEMORY_SCOPE_AGENT);
}
// pack h + step-tag into one self-validating word (tag = step+1; memset-0 == "h(-1) valid")
__device__ __forceinline__ unsigned long long pack_ht(float h, int tag) {
    return ((unsigned long long)(unsigned)tag << 32) | (unsigned long long)__float_as_uint(h);
}

// ============================================================
// K1: fused embedding-gather + input projection GEMM (fp32)
// P layout: [slot][row(64)][gate(1024)] (gate innermost).  (unchanged, proven)
// ============================================================
__global__ __launch_bounds__(256) void proj_kernel(
    const int* __restrict__ sentence, const float* __restrict__ embed,
    const float* __restrict__ Wf_ih, const float* __restrict__ bf,
    const float* __restrict__ Wb_ih, const float* __restrict__ bb,
    float* __restrict__ Pf, float* __restrict__ Pb, int t0f, int t0b)
{
    __shared__ float As[32][BB];
    __shared__ float Ws[32][64];
    const int s   = blockIdx.x;
    const int gb  = blockIdx.y;
    const int dir = gb >> 4;
    const int g0  = (gb & 15) * 64;
    const int tg  = dir ? (t0b + s) : (t0f + s);
    const int tid = threadIdx.x;
    const int tx = tid & 15, ty = tid >> 4;

    const int lrow = tid >> 2;
    const int kq   = tid & 3;
    const int word = sentence[lrow * TT + tg];
    const float* arow = embed + (size_t)word * EE;
    const float* Wih  = dir ? Wb_ih : Wf_ih;
    const float* bias = dir ? bb : bf;
    const float* wrow = Wih + (size_t)(g0 + lrow) * EE;

    float acc[4][4] = {};
    for (int k0 = 0; k0 < EE; k0 += 32) {
        __syncthreads();
        #pragma unroll
        for (int u = 0; u < 8; ++u) {
            const int k  = kq * 8 + u;
            const int kk = k0 + k;
            const bool ok = (kk < EE);
            As[k][lrow] = ok ? arow[kk] : 0.f;
            Ws[k][lrow] = ok ? wrow[kk] : 0.f;
        }
        __syncthreads();
        #pragma unroll
        for (int k = 0; k < 32; ++k) {
            const float4 a = *(const float4*)&As[k][ty * 4];
            const float4 w = *(const float4*)&Ws[k][tx * 4];
            acc[0][0] += a.x*w.x; acc[0][1] += a.x*w.y; acc[0][2] += a.x*w.z; acc[0][3] += a.x*w.w;
            acc[1][0] += a.y*w.x; acc[1][1] += a.y*w.y; acc[1][2] += a.y*w.z; acc[1][3] += a.y*w.w;
            acc[2][0] += a.z*w.x; acc[2][1] += a.z*w.y; acc[2][2] += a.z*w.z; acc[2][3] += a.z*w.w;
            acc[3][0] += a.w*w.x; acc[3][1] += a.w*w.y; acc[3][2] += a.w*w.z; acc[3][3] += a.w*w.w;
        }
    }
    float* Pd = (dir ? Pb : Pf) + (size_t)s * BB * NG;
    const float4 bv = *(const float4*)&bias[g0 + tx * 4];
    #pragma unroll
    for (int i = 0; i < 4; ++i) {
        float4 v;
        v.x = acc[i][0] + bv.x; v.y = acc[i][1] + bv.y;
        v.z = acc[i][2] + bv.z; v.w = acc[i][3] + bv.w;
        *(float4*)(Pd + (size_t)(ty * 4 + i) * NG + g0 + tx * 4) = v;
    }
}

// GEMV core, 4-row variant of the R5..R10-proven math: W in regs, h from LDS,
// partials over this lane's 16-k slice for 4 rows x 4 gates, then a
// recursive-halving butterfly over the 16 s-lanes (static indices).
// End: lanes s, s+4, s+8, s+12 all hold row (s&3)'s 4 full gate sums.
__device__ __forceinline__ void gemv4(const float* __restrict__ base,
                                      const float4 (&wr)[4][4], int s,
                                      float res[4])
{
    float acc[4][4];
    #pragma unroll
    for (int g = 0; g < 4; ++g)
        #pragma unroll
        for (int r = 0; r < 4; ++r) acc[g][r] = 0.f;

    #pragma unroll
    for (int r = 0; r < 4; ++r) {
        const float* hr = base + r * HS + 4 * s;
        const float4 h0 = *(const float4*)(hr + 0);
        const float4 h1 = *(const float4*)(hr + 64);
        const float4 h2 = *(const float4*)(hr + 128);
        const float4 h3 = *(const float4*)(hr + 192);
        #pragma unroll
        for (int g = 0; g < 4; ++g) {
            float a4 = acc[g][r];
            a4 = fmaf(wr[g][0].x, h0.x, a4); a4 = fmaf(wr[g][0].y, h0.y, a4);
            a4 = fmaf(wr[g][0].z, h0.z, a4); a4 = fmaf(wr[g][0].w, h0.w, a4);
            a4 = fmaf(wr[g][1].x, h1.x, a4); a4 = fmaf(wr[g][1].y, h1.y, a4);
            a4 = fmaf(wr[g][1].z, h1.z, a4); a4 = fmaf(wr[g][1].w, h1.w, a4);
            a4 = fmaf(wr[g][2].x, h2.x, a4); a4 = fmaf(wr[g][2].y, h2.y, a4);
            a4 = fmaf(wr[g][2].z, h2.z, a4); a4 = fmaf(wr[g][2].w, h2.w, a4);
            a4 = fmaf(wr[g][3].x, h3.x, a4); a4 = fmaf(wr[g][3].y, h3.y, a4);
            a4 = fmaf(wr[g][3].z, h3.z, a4); a4 = fmaf(wr[g][3].w, h3.w, a4);
            acc[g][r] = a4;
        }
    }
    // round 1 (xor 1): keep rows {(s&1), (s&1)+2}
    float r1[4][2];
    #pragma unroll
    for (int g = 0; g < 4; ++g)
        #pragma unroll
        for (int m = 0; m < 2; ++m) {
            const float sendv = (s & 1) ? acc[g][2*m]   : acc[g][2*m+1];
            const float keepv = (s & 1) ? acc[g][2*m+1] : acc[g][2*m];
            r1[g][m] = keepv + __shfl_xor(sendv, 1);
        }
    // round 2 (xor 2): keep row (s&3); rounds 3/4 (xor 4, 8) sum k-slices
    // across partners with the same (s&3) — plain adds, no muxing.
    #pragma unroll
    for (int g = 0; g < 4; ++g) {
        const float sendv = (s & 2) ? r1[g][0] : r1[g][1];
        const float keepv = (s & 2) ? r1[g][1] : r1[g][0];
        const float r2 = keepv + __shfl_xor(sendv, 2);
        const float r3 = r2 + __shfl_xor(r2, 4);
        res[g] = r3 + __shfl_xor(r3, 8);
    }
}

// ============================================================
// K2: WAVE-SPECIALIZED dual-direction LSTM, 2 BLOCKS PER CU (TLP fix).
// R10 proved W-residency was not the cost: with 1 wave/SIMD every LDS/LLC
// latency and peer-skew spin is fully exposed (~6.5K of 11.6K cyc/step).
// This round: 512 blocks x 256 threads = 2 co-resident blocks/CU = 2
// waves/SIMD (amdgpu_waves_per_eu(2,2): budget 256 VGPR, no spill incentive,
// co-residency guaranteed: 16.6KB LDS x2, ~150 VGPR x2 <= 512, 8 waves/CU).
// Per-thread work halves (4 rows); per-CU totals and LLC traffic unchanged —
// a single-variable occupancy experiment.
// blk&15 = row-group rg (4 rows; same-rg blocks share an XCD since 16≡0 mod 8);
// jg = blk>>4 = dim-group (8 dims). Waves 0-1 = fwd, waves 2-3 = bwd.
// Tag protocol / parity slots / memset-0 init / transitive overwrite-safety:
// verbatim R8..R10 (only the rg-width constant changed).
// ============================================================
__global__ __launch_bounds__(256)
__attribute__((amdgpu_waves_per_eu(2, 2)))
void lstm_kernel(
    const float* __restrict__ Pf, const float* __restrict__ Pb,
    const float* __restrict__ Wf_hh, const float* __restrict__ Wb_hh,
    const int* __restrict__ lengths,
    float* __restrict__ HF, float* __restrict__ HB,
    unsigned long long* __restrict__ hx2,  // [parity][dir][rg16][dim 256][row 4] u64
    float* __restrict__ cbuf,              // [dir][dim 256][row 64]
    int step0, int nsteps)
{
    __shared__ float lds[LDS_FLOATS];    // [buf(u&1)][dir][1040]
    const int blk  = blockIdx.x;
    const int rg   = blk & 15;           // row-group (XCD-residue preserved)
    const int jg   = blk >> 4;           // dim-group 0..31
    const int tid  = threadIdx.x;
    const int w    = tid >> 6;           // wave 0..3
    const int dirw = w >> 1;             // 0 = fwd (waves 0,1), 1 = bwd (waves 2,3)
    const int wh   = w & 1;              // dim half within this direction
    const int lane = tid & 63;
    const int d    = lane >> 4;          // dim-within-wave 0..3
    const int s    = lane & 15;          // k-slice 0..15
    const int rs   = s & 3;              // owned row 0..3 (dup at s, s+4, s+8, s+12)
    const int dg   = jg * 8 + wh * 4 + d;     // global dim 0..255
    const int grow = rg * RPBF + rs;          // global batch row
    const int kb   = tid >> 2;           // stage role: dim base 0..63
    const int rr   = tid & 3;            // stage role: row 0..3

    const float* Whh = dirw ? Wb_hh : Wf_hh;
    const float* P   = dirw ? Pb : Pf;
    float* Hout      = dirw ? HB : HF;
    const int len    = lengths[grow];

    // ---- own direction's W_hh slice -> registers (64 VGPR)
    float4 wR[4][4];
    #pragma unroll
    for (int g = 0; g < 4; ++g) {
        const float* wrow = Whh + (size_t)(g * HD + dg) * HD + 4 * s;
        #pragma unroll
        for (int q = 0; q < 4; ++q)
            wR[g][q] = *(const float4*)(wrow + 64 * q);
    }
    // PIN: opaque asm prevents rematerialization (R9 lesson: only safe when
    // the register budget is explicit — waves_per_eu(2,2) gives 256).
    #pragma unroll
    for (int g = 0; g < 4; ++g)
        #pragma unroll
        for (int q = 0; q < 4; ++q)
            asm volatile("" : "+v"(wR[g][q].x), "+v"(wR[g][q].y),
                              "+v"(wR[g][q].z), "+v"(wR[g][q].w));

    // ---- cell state (own direction only)
    float c0 = cbuf[((size_t)dirw * HD + dg) * BB + grow];

    // ---- prologue: load + verify BOTH dirs h(step0-1) (tag step0, parity (step0+1)&1)
    unsigned long long hF[4], hB[4];
    {
        const unsigned long long* s0F = hx2 + ((size_t)(((step0 + 1) & 1) * 2 + 0) * RGC + rg) * HXS;
        const unsigned long long* s0B = hx2 + ((size_t)(((step0 + 1) & 1) * 2 + 1) * RGC + rg) * HXS;
        #pragma unroll
        for (int it = 0; it < 4; ++it) {
            hF[it] = ldg_llc_u64(&s0F[(kb + 64 * it) * 4 + rr]);
            hB[it] = ldg_llc_u64(&s0B[(kb + 64 * it) * 4 + rr]);
        }
        #pragma unroll
        for (int it = 0; it < 4; ++it) {
            unsigned long long v = hF[it];
            if ((int)(v >> 32) != step0) {
                const unsigned long long* a = &s0F[(kb + 64 * it) * 4 + rr];
                do { v = ldg_llc_u64(a); } while ((int)(v >> 32) != step0);
            }
            hF[it] = v;
            v = hB[it];
            if ((int)(v >> 32) != step0) {
                const unsigned long long* a = &s0B[(kb + 64 * it) * 4 + rr];
                do { v = ldg_llc_u64(a); } while ((int)(v >> 32) != step0);
            }
            hB[it] = v;
        }
    }

    for (int u = 0; u < nsteps; ++u) {
        const int gs   = step0 + u;
        const int pbt  = TT - 1 - gs;    // original time index for bwd
        const int p    = dirw ? pbt : gs;
        const int slot = dirw ? (nsteps - 1 - u) : u;

        // P terms (own dir, h-independent), issued early
        const float* Pp = P + ((size_t)slot * BB + grow) * NG + dg;
        const float pi = Pp[0], pf = Pp[256], pg = Pp[512], po = Pp[768];

        // stage verified h(gs-1), both dirs -> LDS buf[u&1]
        float* bufF = lds + (u & 1) * (2 * LDSF);
        float* bufB = bufF + LDSF;
        #pragma unroll
        for (int it = 0; it < 4; ++it) {
            bufF[rr * HS + kb + 64 * it] =
                __uint_as_float((unsigned)(hF[it] & 0xffffffffull));
            bufB[rr * HS + kb + 64 * it] =
                __uint_as_float((unsigned)(hB[it] & 0xffffffffull));
        }
        __syncthreads();   // the ONLY barrier: all staged; bounds skew < 1 iter

        // GEMV (own direction, W pinned in registers)
        float res[4];
        gemv4(dirw ? bufB : bufF, wR, s, res);

        // cell math (one row, one dim, own dir)
        const float ig = 1.f / (1.f + expf(-(res[0] + pi)));
        const float fg = 1.f / (1.f + expf(-(res[1] + pf)));
        const float og = 1.f / (1.f + expf(-(res[3] + po)));
        const float gt = tanhf(res[2] + pg);
        float cn = fg * c0 + ig * gt;
        float hn = og * tanhf(cn);
        if (dirw) {                      // bwd rows inactive until p < len
            const bool v0 = (pbt < len);
            c0 = v0 ? cn : c0;  hn = v0 ? hn : 0.f;
        } else {
            c0 = cn;
        }

        // publish (h, tag gs+1), fire-and-forget; lazy H write
        if (s < 4) {
            stg_llc_u64(&hx2[((size_t)((gs & 1) * 2 + dirw) * RGC + rg) * HXS
                             + (size_t)dg * RPBF + rs], pack_ht(hn, gs + 1));
            Hout[((size_t)p * HD + dg) * BB + grow] = hn;
        }

        // issue + verify next step's h(gs) (tag gs+1, parity gs&1), both dirs.
        // Common path: one OR-reduced check; slow path: per-word spin.
        if (u + 1 < nsteps) {
            const unsigned long long* sF = hx2 + ((size_t)((gs & 1) * 2 + 0) * RGC + rg) * HXS;
            const unsigned long long* sB = hx2 + ((size_t)((gs & 1) * 2 + 1) * RGC + rg) * HXS;
            #pragma unroll
            for (int it = 0; it < 4; ++it) {
                hF[it] = ldg_llc_u64(&sF[(kb + 64 * it) * 4 + rr]);
                hB[it] = ldg_llc_u64(&sB[(kb + 64 * it) * 4 + rr]);
            }
            unsigned bad = 0;
            #pragma unroll
            for (int it = 0; it < 4; ++it) {
                bad |= (unsigned)(hF[it] >> 32) ^ (unsigned)(gs + 1);
                bad |= (unsigned)(hB[it] >> 32) ^ (unsigned)(gs + 1);
            }
            if (bad) {
                #pragma unroll
                for (int it = 0; it < 4; ++it) {
                    unsigned long long v = hF[it];
                    if ((int)(v >> 32) != gs + 1) {
                        const unsigned long long* a = &sF[(kb + 64 * it) * 4 + rr];
                        do { v = ldg_llc_u64(a); } while ((int)(v >> 32) != gs + 1);
                    }
                    hF[it] = v;
                    v = hB[it];
                    if ((int)(v >> 32) != gs + 1) {
                        const unsigned long long* a = &sB[(kb + 64 * it) * 4 + rr];
                        do { v = ldg_llc_u64(a); } while ((int)(v >> 32) != gs + 1);
                    }
                    hB[it] = v;
                }
            }
        }
        // no second barrier: stage(u+1) writes buf[(u+1)&1], disjoint from
        // buf[u&1] that any slower wave may still be reading in gemv(u).
    }

    if (s < 4)
        cbuf[((size_t)dirw * HD + dg) * BB + grow] = c0;
}

// ============================================================
// K3: emissions = [hf|hb] @ W_out^T + b_out -> emis[t][b][20]
// H layout [t][d][b].  (unchanged, proven)
// ============================================================
__global__ __launch_bounds__(256) void emis_kernel(
    const float* __restrict__ HF, const float* __restrict__ HB,
    const float* __restrict__ W_out, const float* __restrict__ b_out,
    float* __restrict__ emis)
{
    const int t = blockIdx.x;
    const int b = threadIdx.x & 63;
    int jg = threadIdx.x >> 6;
    jg = __builtin_amdgcn_readfirstlane(jg);

    float acc[5];
    #pragma unroll
    for (int u = 0; u < 5; ++u) acc[u] = b_out[jg + 4 * u];

    const float* hf = HF + (size_t)t * HD * BB + b;
    const float* hb = HB + (size_t)t * HD * BB + b;
    for (int k = 0; k < HD; ++k) {
        const float hv = hf[(size_t)k * BB];
        #pragma unroll
        for (int u = 0; u < 5; ++u)
            acc[u] = fmaf(hv, W_out[(size_t)(jg + 4 * u) * 512 + k], acc[u]);
    }
    for (int k = 0; k < HD; ++k) {
        const float hv = hb[(size_t)k * BB];
        #pragma unroll
        for (int u = 0; u < 5; ++u)
            acc[u] = fmaf(hv, W_out[(size_t)(jg + 4 * u) * 512 + HD + k], acc[u]);
    }
    #pragma unroll
    for (int u = 0; u < 5; ++u)
        emis[((size_t)t * BB + b) * KK + jg + 4 * u] = acc[u];
}

// ============================================================
// K4: Viterbi per batch row; exact first-max argmax; bp in LDS. (unchanged)
// ============================================================
__global__ __launch_bounds__(64) void viterbi_kernel(
    const float* __restrict__ emis, const int* __restrict__ lengths,
    const float* __restrict__ trans, const int* __restrict__ stop_id_p,
    float* __restrict__ out)
{
    __shared__ float tr[KK * KK];
    __shared__ float delta[KK], nd[KK];
    __shared__ unsigned char bp[TT][KK];
    const int b = blockIdx.x;
    const int tid = threadIdx.x;
    for (int i = tid; i < KK * KK; i += 64) tr[i] = trans[i];
    if (tid < KK) delta[tid] = 0.f;
    const int len = lengths[b];
    __syncthreads();

    for (int t = 0; t < TT; ++t) {
        if (tid < KK) {
            if (t < len) {
                float best = delta[0] + tr[tid * KK + 0];
                int am = 0;
                for (int p2 = 1; p2 < KK; ++p2) {
                    const float v = delta[p2] + tr[tid * KK + p2];
                    if (v > best) { best = v; am = p2; }
                }
                nd[tid] = best + emis[((size_t)t * BB + b) * KK + tid];
                bp[t][tid] = (unsigned char)am;
            } else {
                nd[tid] = delta[tid];
                bp[t][tid] = (unsigned char)tid;
            }
        }
        __syncthreads();
        if (tid < KK) delta[tid] = nd[tid];
        __syncthreads();
    }

    if (tid == 0) {
        const int stop_id = *stop_id_p;
        float best = delta[0] + tr[stop_id * KK + 0];
        int bl = 0;
        for (int jx = 1; jx < KK; ++jx) {
            const float v = delta[jx] + tr[stop_id * KK + jx];
            if (v > best) { best = v; bl = jx; }
        }
        out[b] = best;
        float* pout = out + BB + (size_t)b * (TT + 1);
        pout[TT] = (float)bl;
        int tag = bl;
        for (int t = TT - 1; t >= 0; --t) {
            tag = bp[t][tag];
            pout[t] = (float)tag;
        }
    }
}

// ============================================================
extern "C" void kernel_launch(void* const* d_in, const int* in_sizes, int n_in,
                              void* d_out, int out_size, void* d_ws, size_t ws_size,
                              hipStream_t stream) {
    const int*   sentence = (const int*)d_in[0];
    const int*   lengths  = (const int*)d_in[1];
    const int*   stop_id  = (const int*)d_in[3];
    const float* embed    = (const float*)d_in[4];
    const float* Wf_ih    = (const float*)d_in[5];
    const float* Wf_hh    = (const float*)d_in[6];
    const float* bf       = (const float*)d_in[7];
    const float* Wb_ih    = (const float*)d_in[8];
    const float* Wb_hh    = (const float*)d_in[9];
    const float* bb       = (const float*)d_in[10];
    const float* W_out    = (const float*)d_in[11];
    const float* b_out    = (const float*)d_in[12];
    const float* trans    = (const float*)d_in[13];
    float* out = (float*)d_out;

    const size_t hf_elems   = (size_t)TT * HD * BB;
    const size_t emis_elems = (size_t)TT * BB * KK;
    const size_t hx_u64     = (size_t)2 * 2 * RGC * HD * RPBF; // 65536 u64
    const size_t cbuf_elems = (size_t)2 * HD * BB;             // 32768
    const size_t fixed_bytes = (2 * hf_elems + emis_elems + cbuf_elems) * 4 + hx_u64 * 8;

    int CH = 0;
    const int cands[6] = {256, 128, 64, 32, 16, 8};
    for (int i = 0; i < 6; ++i) {
        const size_t need = fixed_bytes + 2ull * cands[i] * BB * NG * 4;
        if (need <= ws_size) { CH = cands[i]; break; }
    }
    if (CH == 0) return;

    float* Pf    = (float*)d_ws;
    float* Pb    = Pf + (size_t)CH * BB * NG;
    float* HF    = Pb + (size_t)CH * BB * NG;
    float* HB    = HF + hf_elems;
    float* emis  = HB + hf_elems;
    unsigned long long* hx2 = (unsigned long long*)(emis + emis_elems); // 8B-aligned (even float offset)
    float* cbuf  = (float*)(hx2 + hx_u64);

    // zero hx2 (tags 0 == valid initial h(-1)) + cbuf — contiguous region
    hipMemsetAsync(hx2, 0, hx_u64 * 8 + cbuf_elems * 4, stream);

    const int nch = TT / CH;
    for (int c = 0; c < nch; ++c) {
        const int t0f = c * CH;
        const int t0b = TT - (c + 1) * CH;
        proj_kernel<<<dim3(CH, 32), 256, 0, stream>>>(
            sentence, embed, Wf_ih, bf, Wb_ih, bb, Pf, Pb, t0f, t0b);
        lstm_kernel<<<dim3(512), 256, 0, stream>>>(
            Pf, Pb, Wf_hh, Wb_hh, lengths, HF, HB, hx2, cbuf, c * CH, CH);
    }
    emis_kernel<<<dim3(TT), 256, 0, stream>>>(HF, HB, W_out, b_out, emis);
    viterbi_kernel<<<dim3(BB), 64, 0, stream>>>(emis, lengths, trans, stop_id, out);
}